// Round 2
// baseline (1465408.984 us; speedup 1.0000x reference)
//
#include <hip/hip_runtime.h>
#include <math.h>

#define H    256
#define G4H  1024
#define CIN  512
#define BB   16
#define TT   2048
#define CHUNK 256
#define NPH  8   // TT/CHUNK

typedef unsigned long long ull;

// ---- workspace layout (in floats) ----
#define OFF_WQ      ((size_t)0)                        // 131072 float4 = 524288 floats
#define OFF_PROJF   ((size_t)524288)                   // 4194304
#define OFF_PROJB   ((size_t)4718592)                  // 4194304
#define OFF_HBUF    ((size_t)8912896)                  // 16777216
#define OFF_STATS   ((size_t)25690112)                 // 1024
#define OFF_CSTATE  ((size_t)25691136)                 // 8192
#define OFF_HX      ((size_t)25699328)                 // 16384 ull (slow/LLC exchange)
#define OFF_W2      ((size_t)25732096)                 // 1024
#define OFF_B2      ((size_t)25733120)                 // 16
#define OFF_SAMP    ((size_t)25733136)                 // 32768
#define OFF_XCD     ((size_t)25765904)                 // 256 ints (per-WG XCD table)
#define OFF_HXF     ((size_t)25766160)                 // 16384 ull (fast/L2 exchange)
#define OFF_HLAST   ((size_t)25798928)                 // 8192 (cross-dispatch handoff)

#define REP16(X) X(0) X(1) X(2) X(3) X(4) X(5) X(6) X(7) X(8) X(9) X(10) X(11) \
  X(12) X(13) X(14) X(15)

// fast transcendentals for the LSTM cell (v_exp_f32 / v_rcp_f32 based).
__device__ __forceinline__ float frcp_(float x) { return __builtin_amdgcn_rcpf(x); }
__device__ __forceinline__ float fsig_(float x) { return frcp_(1.f + __expf(-x)); }
__device__ __forceinline__ float ftanh_(float x) {
  float a = fabsf(x);
  float e = __expf(-2.f * a);
  float t = (1.f - e) * frcp_(1.f + e);
  return copysignf(t, x);
}

// L1-bypassing, L2-hitting 8B load (sc0 only: coherent within the XCD's L2).
__device__ __forceinline__ ull ld_l2(const ull* p) {
  ull r;
  asm volatile("global_load_dwordx2 %0, %1, off sc0\n\ts_waitcnt vmcnt(0)"
               : "=v"(r) : "v"(p));
  return r;
}

// ---------------- K0: repack Whh; zero stats + exchange tag words ----------------
// wq float4 idx = (dir*4+kq)*16384 + q*1024 + gate*256 + s*32 + jl
__global__ __launch_bounds__(256) void k0_init(
    const float* __restrict__ WhhF, const float* __restrict__ WhhB,
    float4* __restrict__ wq, float* __restrict__ stats,
    int* __restrict__ hxw, int* __restrict__ hxfw, int* __restrict__ xcdtab) {
  int idx = blockIdx.x * 256 + threadIdx.x;
  if (idx < 131072) {
    int jl = idx & 31, s = (idx >> 5) & 7, gate = (idx >> 8) & 3;
    int q = (idx >> 10) & 15, kq = (idx >> 14) & 3, dir = idx >> 16;
    int row = gate * 256 + s * 32 + jl;
    int col = kq * 64 + q * 4;
    const float* W = (dir ? WhhB : WhhF) + (size_t)row * H + col;
    wq[idx] = make_float4(W[0], W[1], W[2], W[3]);
  }
  if (idx < 1024) stats[idx] = 0.f;
  if (idx < 32768) hxw[idx] = 0;    // slow-buffer tags=0 < any target>=1
  if (idx < 32768) hxfw[idx] = 0;   // fast-buffer tags=0
  if (idx < 256) xcdtab[idx] = 0;   // epoch 0 < first epoch 1
}

// ---------------- K1: proj[tc][b][g] = sum_c x[b][c][t] * Wih[g][c] + bih[g]+bhh[g] ----------------
// register double-buffered global->LDS staging; W staging via float4.
__global__ __launch_bounds__(256) void k1_proj(
    const float* __restrict__ x,
    const float* __restrict__ WihF, const float* __restrict__ bihF, const float* __restrict__ bhhF,
    const float* __restrict__ WihB, const float* __restrict__ bihB, const float* __restrict__ bhhB,
    float* __restrict__ projF, float* __restrict__ projB, int t0f, int t0b) {
  __shared__ __align__(16) float Xs[16][68];
  __shared__ __align__(16) float Ws[16][68];
  int tid = threadIdx.x;
  int b = blockIdx.z & 15, dir = blockIdx.z >> 4;
  const float* Wih = dir ? WihB : WihF;
  const float* bih = dir ? bihB : bihF;
  const float* bhh = dir ? bhhB : bhhF;
  float* proj = dir ? projB : projF;
  int tbase = (dir ? t0b : t0f) + blockIdx.x * 64;
  int gbase = blockIdx.y * 64;
  int tx = tid & 15, ty = tid >> 4;
  float acc[4][4];
#pragma unroll
  for (int i = 0; i < 4; i++)
#pragma unroll
    for (int j = 0; j < 4; j++) acc[i][j] = 0.f;

  int lt = tid & 63, lk = tid >> 6;     // X loader: 4 c-rows x 64 t (coalesced)
  int wg = tid >> 2, wc = tid & 3;      // W loader: 64 g-rows x one float4 of c
  const float* xb = x + (size_t)b * CIN * TT + tbase + lt;
  const float* wp = Wih + (size_t)(gbase + wg) * CIN + 4 * wc;

  float rx0 = xb[(size_t)(lk)      * TT];
  float rx1 = xb[(size_t)(lk + 4)  * TT];
  float rx2 = xb[(size_t)(lk + 8)  * TT];
  float rx3 = xb[(size_t)(lk + 12) * TT];
  float4 rw = *(const float4*)(wp);

  for (int c0 = 0; c0 < CIN; c0 += 16) {
    __syncthreads();
    Xs[lk     ][lt] = rx0;
    Xs[lk + 4 ][lt] = rx1;
    Xs[lk + 8 ][lt] = rx2;
    Xs[lk + 12][lt] = rx3;
    Ws[4 * wc    ][wg] = rw.x;
    Ws[4 * wc + 1][wg] = rw.y;
    Ws[4 * wc + 2][wg] = rw.z;
    Ws[4 * wc + 3][wg] = rw.w;
    __syncthreads();
    if (c0 + 16 < CIN) {
      rx0 = xb[(size_t)(c0 + 16 + lk)      * TT];
      rx1 = xb[(size_t)(c0 + 16 + lk + 4)  * TT];
      rx2 = xb[(size_t)(c0 + 16 + lk + 8)  * TT];
      rx3 = xb[(size_t)(c0 + 16 + lk + 12) * TT];
      rw  = *(const float4*)(wp + c0 + 16);
    }
#pragma unroll
    for (int kk = 0; kk < 16; kk++) {
      float4 av = *(const float4*)&Xs[kk][tx * 4];
      float4 bv = *(const float4*)&Ws[kk][ty * 4];
      acc[0][0] += av.x * bv.x; acc[0][1] += av.x * bv.y; acc[0][2] += av.x * bv.z; acc[0][3] += av.x * bv.w;
      acc[1][0] += av.y * bv.x; acc[1][1] += av.y * bv.y; acc[1][2] += av.y * bv.z; acc[1][3] += av.y * bv.w;
      acc[2][0] += av.z * bv.x; acc[2][1] += av.z * bv.y; acc[2][2] += av.z * bv.z; acc[2][3] += av.z * bv.w;
      acc[3][0] += av.w * bv.x; acc[3][1] += av.w * bv.y; acc[3][2] += av.w * bv.z; acc[3][3] += av.w * bv.w;
    }
  }
  int g0 = gbase + ty * 4;
  float bias0 = bih[g0 + 0] + bhh[g0 + 0];
  float bias1 = bih[g0 + 1] + bhh[g0 + 1];
  float bias2 = bih[g0 + 2] + bhh[g0 + 2];
  float bias3 = bih[g0 + 3] + bhh[g0 + 3];
#pragma unroll
  for (int i = 0; i < 4; i++) {
    int tc = blockIdx.x * 64 + tx * 4 + i;
    float4 st = make_float4(acc[i][0] + bias0, acc[i][1] + bias1,
                            acc[i][2] + bias2, acc[i][3] + bias3);
    *(float4*)(proj + ((size_t)tc * BB + b) * G4H + g0) = st;
  }
}

// ---------------- K2: LSTM recurrence ----------------
// 8 sibling WGs x 512 thr per (dir,b). Thread: jl=tid&31, gate=(tid>>5)&3, kq=tid>>7.
// 16 float4 weights per thread, asm-pinned (register-resident, verified via FETCH).
// r2 exchange (3 tiers):
//   - own slice: written straight to LDS at publish (no memory trip)
//   - same-XCD sibling (runtime-verified via HW_REG_XCC_ID table): plain store ->
//     sc0-load poll through the shared XCD L2 (~200cy instead of LLC ~700cy)
//   - cross-XCD / fallback: agent-scope atomics via LLC (as r1); bounded fast-spin
//     falls back to slow so a placement surprise degrades instead of hanging
//   - cross-dispatch step-0 handoff: plain hlast buffer (stream order = visible)
__global__ __launch_bounds__(512, 1) void k2_rec(
    const float4* __restrict__ wq, const float* __restrict__ projF,
    const float* __restrict__ projB, float* __restrict__ hbuf,
    ull* __restrict__ hx2, ull* __restrict__ hxF, float* __restrict__ hlast,
    int* __restrict__ xcdtab, float* __restrict__ cstate,
    float* __restrict__ stats, int t0f, int t0b, int first, int ebase, int epoch) {
  __shared__ __align__(16) float h_lds[256];
  __shared__ float pbuf[512];
  __shared__ int sxcd[8];
  __shared__ int myxcd_s;
  const int tid = threadIdx.x;
  const int l = tid & 63, w = tid >> 6;
  const int jl = tid & 31, gate = (tid >> 5) & 3, kq = tid >> 7;
  const int bx = blockIdx.x;
  const int grp = bx & 31, s = bx >> 5;     // 8 siblings: {g, g+32, ..., g+224}
  const int dir = grp >> 4, b = grp & 15;
  const int row = gate * 256 + s * 32 + jl; // gate row [0,1024)

  // ---- XCD discovery: publish own entry, then poll the 8 siblings' entries ----
  if (tid == 0) {
    unsigned xr;
    asm volatile("s_getreg_b32 %0, hwreg(HW_REG_XCC_ID)" : "=s"(xr));
    int x = (int)(xr & 0xf);
    myxcd_s = x;
    __hip_atomic_store(&xcdtab[bx], (epoch << 8) | x,
                       __ATOMIC_RELAXED, __HIP_MEMORY_SCOPE_AGENT);
  }
  if (tid < 8) {
    int* ep = &xcdtab[grp + 32 * tid];
    int v = __hip_atomic_load(ep, __ATOMIC_RELAXED, __HIP_MEMORY_SCOPE_AGENT);
    while ((v >> 8) != epoch)
      v = __hip_atomic_load(ep, __ATOMIC_RELAXED, __HIP_MEMORY_SCOPE_AGENT);
    sxcd[tid] = v & 0xff;
  }

  const float4* wbase = wq + (size_t)(dir * 4 + kq) * 16384 + gate * 256 + s * 32 + jl;
#define WDECL(i) float wx##i, wy##i, wz##i, ww##i; \
  { float4 t_ = wbase[(size_t)(i) * 1024]; \
    wx##i = t_.x; wy##i = t_.y; wz##i = t_.z; ww##i = t_.w; } \
  asm volatile("" : "+v"(wx##i), "+v"(wy##i), "+v"(wz##i), "+v"(ww##i));
  REP16(WDECL)
#undef WDECL

  float c = 0.f, s1 = 0.f, s2 = 0.f;
  if (w == 0 && l < 32 && !first) c = cstate[grp * 256 + s * 32 + l];

  const float* pbase = dir ? projB : projF;
  float pv = 0.f;
  if (kq == 0) {
    int tc0 = dir ? (CHUNK - 1) : 0;
    pv = pbase[((size_t)tc0 * BB + b) * G4H + row];
  }

  __syncthreads();                          // sxcd/myxcd ready
  const bool fastok = (tid < 256) && (sxcd[tid >> 5] == myxcd_s);

  for (int step = 0; step < CHUNK; ++step) {
    int abs = ebase + step;

    // acquire h_{abs-1}
    if (tid < 256) {
      if (abs == 0) {
        h_lds[tid] = 0.f;
      } else if (step == 0) {
        h_lds[tid] = hlast[grp * 256 + tid];  // prev dispatch (stream-ordered)
      } else if ((tid >> 5) != s) {           // own slice already in h_lds
        size_t off = (size_t)((abs - 1) & 1) * 8192 + grp * 256 + tid;
        ull wd = 0;
        if (fastok) {
          const ull* srcF = hxF + off;
          wd = ld_l2(srcF);
          int tries = 0;
          while ((int)(wd >> 32) < abs && ++tries < 8192) wd = ld_l2(srcF);
        }
        if ((int)(wd >> 32) < abs) {          // cross-XCD sibling or fallback
          ull* src = hx2 + off;
          wd = __hip_atomic_load(src, __ATOMIC_RELAXED, __HIP_MEMORY_SCOPE_AGENT);
          while ((int)(wd >> 32) < abs)
            wd = __hip_atomic_load(src, __ATOMIC_RELAXED, __HIP_MEMORY_SCOPE_AGENT);
        }
        h_lds[tid] = __uint_as_float((unsigned)wd);
      }
    }
    __syncthreads();                          // A: h ready

    float acc = (kq == 0) ? pv : 0.f;
    const float4* h4p = ((const float4*)h_lds) + (kq << 4);
#define WFMA(i) { float4 hv = h4p[i]; \
    acc += wx##i * hv.x + wy##i * hv.y + wz##i * hv.z + ww##i * hv.w; }
    REP16(WFMA)
#undef WFMA
    pbuf[tid] = acc;
    __syncthreads();                          // B: partials ready (h_lds reads done)

    if (w == 0 && l < 32) {
      float gi = pbuf[l]       + pbuf[128 + l] + pbuf[256 + l] + pbuf[384 + l];
      float gf = pbuf[32 + l]  + pbuf[160 + l] + pbuf[288 + l] + pbuf[416 + l];
      float gg = pbuf[64 + l]  + pbuf[192 + l] + pbuf[320 + l] + pbuf[448 + l];
      float go = pbuf[96 + l]  + pbuf[224 + l] + pbuf[352 + l] + pbuf[480 + l];
      float ig = fsig_(gi);
      float fg = fsig_(gf);
      float gz = ftanh_(gg);
      float og = fsig_(go);
      c = fg * c + ig * gz;
      float h = og * ftanh_(c);
      s1 += h; s2 += h * h;
      int j = s * 32 + l;
      h_lds[j] = h;                           // own-slice local publish (safe: after B)
      ull wd = ((ull)(unsigned)(abs + 1) << 32) | (ull)__float_as_uint(h);
      size_t off = (size_t)(abs & 1) * 8192 + grp * 256 + j;
      // fast publish first (same-XCD consumers detect via L2)
      __hip_atomic_store(hxF + off, wd, __ATOMIC_RELAXED, __HIP_MEMORY_SCOPE_WORKGROUP);
      // slow publish (device-coherent fallback)
      __hip_atomic_store(hx2 + off, wd, __ATOMIC_RELAXED, __HIP_MEMORY_SCOPE_AGENT);
      if (step == CHUNK - 1) hlast[grp * 256 + j] = h;  // next-dispatch handoff
      // streaming store off the critical path (after publish)
      int tc = dir ? (CHUNK - 1 - step) : step;
      int t = (dir ? t0b : t0f) + tc;
      hbuf[((size_t)t * BB + b) * 512 + dir * 256 + j] = h;
    }
    if (kq == 0 && step + 1 < CHUNK) {        // prefetch next proj
      int tcn = dir ? (CHUNK - 2 - step) : (step + 1);
      pv = pbase[((size_t)tcn * BB + b) * G4H + row];
    }
    // no bottom barrier: next poll + barrier A separates steps
  }

  if (w == 0 && l < 32) {
    cstate[grp * 256 + s * 32 + l] = c;
    atomicAdd(&stats[dir * 256 + s * 32 + l], s1);
    atomicAdd(&stats[512 + dir * 256 + s * 32 + l], s2);
  }
}

// ---------------- K3: fold BN into linear ----------------
__global__ __launch_bounds__(512) void k3_prep(
    const float* __restrict__ stats, const float* __restrict__ gamma,
    const float* __restrict__ beta, const float* __restrict__ Wlin,
    const float* __restrict__ blin, float* __restrict__ w2, float* __restrict__ b2) {
  __shared__ float r0[512], r1[512];
  int ch = threadIdx.x;
  float mean = stats[ch] * (1.f / 32768.f);
  float var  = stats[512 + ch] * (1.f / 32768.f) - mean * mean;
  float sc = gamma[ch] * rsqrtf(var + 1e-5f);
  float w0 = Wlin[ch], w1 = Wlin[512 + ch];
  w2[ch] = w0 * sc; w2[512 + ch] = w1 * sc;
  float tt = beta[ch] - mean * sc;
  r0[ch] = w0 * tt; r1[ch] = w1 * tt;
  __syncthreads();
  for (int off = 256; off > 0; off >>= 1) {
    if (ch < off) { r0[ch] += r0[ch + off]; r1[ch] += r1[ch + off]; }
    __syncthreads();
  }
  if (ch == 0) { b2[0] = blin[0] + r0[0]; b2[1] = blin[1] + r1[0]; }
}

// ---------------- K4: posterior + gumbel hard sample; one wave per (b,t) ----------------
__global__ __launch_bounds__(256) void k4_post(
    const float* __restrict__ hbuf, const float* __restrict__ w2,
    const float* __restrict__ b2, const float* __restrict__ u,
    const float* __restrict__ e, float* __restrict__ post,
    float* __restrict__ samp) {
  int wid = (blockIdx.x * 256 + threadIdx.x) >> 6;
  int lane = threadIdx.x & 63;
  int b = wid >> 11, t = wid & 2047;
  const float* hr = hbuf + ((size_t)t * BB + b) * 512;
  int c0 = lane * 8;
  float4 h0 = *(const float4*)(hr + c0);
  float4 h1 = *(const float4*)(hr + c0 + 4);
  float4 wa = *(const float4*)(w2 + c0);
  float4 wb = *(const float4*)(w2 + c0 + 4);
  float4 va = *(const float4*)(w2 + 512 + c0);
  float4 vb = *(const float4*)(w2 + 512 + c0 + 4);
  float d0 = h0.x * wa.x + h0.y * wa.y + h0.z * wa.z + h0.w * wa.w
           + h1.x * wb.x + h1.y * wb.y + h1.z * wb.z + h1.w * wb.w;
  float d1 = h0.x * va.x + h0.y * va.y + h0.z * va.z + h0.w * va.w
           + h1.x * vb.x + h1.y * vb.y + h1.z * vb.z + h1.w * vb.w;
#pragma unroll
  for (int off = 32; off > 0; off >>= 1) {
    d0 += __shfl_xor(d0, off, 64);
    d1 += __shfl_xor(d1, off, 64);
  }
  if (lane == 0) {
    float z0 = (d0 + b2[0]) * 0.1f, z1 = (d1 + b2[1]) * 0.1f;
    float m = fmaxf(z0, z1);
    float e0 = expf(z0 - m), e1 = expf(z1 - m);
    float inv = 1.f / (e0 + e1);
    float p0 = e0 * inv, p1 = e1 * inv;
    size_t o = (size_t)b * TT + t;
    post[o * 2] = p0; post[o * 2 + 1] = p1;
    float u0 = u[o * 2], u1 = u[o * 2 + 1];
    float g0 = -logf(-logf(u0 + 1e-20f) + 1e-20f);
    float g1 = -logf(-logf(u1 + 1e-20f) + 1e-20f);
    float a0 = logf(p0) + g0, a1 = logf(p1) + g1;
    samp[o] = (a1 > a0) ? e[o] : 0.f;  // strict >: np.argmax tie -> class 0
  }
}

// ---------------- K5: 3x median-of-5 (reflect pad), one WG per b ----------------
#define MSWAP(a, b) { float lo_ = fminf(a, b); b = fmaxf(a, b); a = lo_; }
__global__ __launch_bounds__(256) void k5_median(
    const float* __restrict__ samp, float* __restrict__ mask) {
  __shared__ float buf[2][TT];
  int b = blockIdx.x, tid = threadIdx.x;
  for (int i = tid; i < TT; i += 256) buf[0][i] = samp[(size_t)b * TT + i];
  __syncthreads();
  int src = 0;
  for (int pass = 0; pass < 3; ++pass) {
    for (int i = tid; i < TT; i += 256) {
      float v0, v1, v2, v3, v4;
      {
        int i0 = i - 2; i0 = i0 < 0 ? -i0 : i0;
        int i1 = i - 1; i1 = i1 < 0 ? -i1 : i1;
        int i3 = i + 1; i3 = i3 > TT - 1 ? 2 * (TT - 1) - i3 : i3;
        int i4 = i + 2; i4 = i4 > TT - 1 ? 2 * (TT - 1) - i4 : i4;
        v0 = buf[src][i0]; v1 = buf[src][i1]; v2 = buf[src][i];
        v3 = buf[src][i3]; v4 = buf[src][i4];
      }
      MSWAP(v0, v1); MSWAP(v3, v4); MSWAP(v2, v4); MSWAP(v2, v3);
      MSWAP(v1, v4); MSWAP(v0, v3); MSWAP(v0, v2); MSWAP(v1, v3);
      MSWAP(v1, v2);
      buf[1 - src][i] = v2;
    }
    __syncthreads();
    src = 1 - src;
  }
  for (int i = tid; i < TT; i += 256) mask[(size_t)b * TT + i] = buf[src][i];
}

extern "C" void kernel_launch(void* const* d_in, const int* in_sizes, int n_in,
                              void* d_out, int out_size, void* d_ws, size_t ws_size,
                              hipStream_t stream) {
  const float* x    = (const float*)d_in[0];
  const float* e    = (const float*)d_in[1];
  const float* u    = (const float*)d_in[2];
  const float* WihF = (const float*)d_in[3];
  const float* WhhF = (const float*)d_in[4];
  const float* bihF = (const float*)d_in[5];
  const float* bhhF = (const float*)d_in[6];
  const float* WihB = (const float*)d_in[7];
  const float* WhhB = (const float*)d_in[8];
  const float* bihB = (const float*)d_in[9];
  const float* bhhB = (const float*)d_in[10];
  const float* gamma= (const float*)d_in[11];
  const float* beta = (const float*)d_in[12];
  const float* Wlin = (const float*)d_in[13];
  const float* blin = (const float*)d_in[14];

  float* ws = (float*)d_ws;
  float4* wq    = (float4*)(ws + OFF_WQ);
  float* projF  = ws + OFF_PROJF;
  float* projB  = ws + OFF_PROJB;
  float* hbuf   = ws + OFF_HBUF;
  float* stats  = ws + OFF_STATS;
  float* cstate = ws + OFF_CSTATE;
  ull*   hx2    = (ull*)(ws + OFF_HX);
  float* w2     = ws + OFF_W2;
  float* b2     = ws + OFF_B2;
  float* samp   = ws + OFF_SAMP;
  int*   xcdtab = (int*)(ws + OFF_XCD);
  ull*   hxF    = (ull*)(ws + OFF_HXF);
  float* hlast  = ws + OFF_HLAST;

  float* post = (float*)d_out;
  float* mask = (float*)d_out + (size_t)BB * TT * 2;

  hipLaunchKernelGGL(k0_init, dim3(512), dim3(256), 0, stream,
                     WhhF, WhhB, wq, stats, (int*)hx2, (int*)hxF, xcdtab);
  for (int p = 0; p < NPH; ++p) {
    int t0f = p * CHUNK;
    int t0b = (NPH - 1 - p) * CHUNK;
    hipLaunchKernelGGL(k1_proj, dim3(CHUNK / 64, 16, 32), dim3(256), 0, stream,
                       x, WihF, bihF, bhhF, WihB, bihB, bhhB, projF, projB, t0f, t0b);
    hipLaunchKernelGGL(k2_rec, dim3(256), dim3(512), 0, stream,
                       wq, projF, projB, hbuf, hx2, hxF, hlast, xcdtab,
                       cstate, stats, t0f, t0b, p == 0 ? 1 : 0, p * CHUNK, p + 1);
  }
  hipLaunchKernelGGL(k3_prep, dim3(1), dim3(512), 0, stream,
                     stats, gamma, beta, Wlin, blin, w2, b2);
  hipLaunchKernelGGL(k4_post, dim3(8192), dim3(256), 0, stream,
                     hbuf, w2, b2, u, e, post, samp);
  hipLaunchKernelGGL(k5_median, dim3(16), dim3(256), 0, stream, samp, mask);
}

// Round 3
// 3082.371 us; speedup vs baseline: 475.4161x; 475.4161x over previous
//
#include <hip/hip_runtime.h>
#include <math.h>

#define H    256
#define G4H  1024
#define CIN  512
#define BB   16
#define TT   2048
#define CHUNK 128
#define NPH  16   // TT/CHUNK

typedef unsigned long long ull;

// ---- workspace layout (in floats) ----
#define OFF_WQ      ((size_t)0)                        // 524288
#define OFF_PF0     ((size_t)524288)                   // 2097152 (proj fwd, parity 0)
#define OFF_PF1     ((size_t)2621440)                  // 2097152 (proj fwd, parity 1)
#define OFF_PB0     ((size_t)4718592)                  // 2097152 (proj bwd, parity 0)
#define OFF_PB1     ((size_t)6815744)                  // 2097152 (proj bwd, parity 1)
#define OFF_HBUF    ((size_t)8912896)                  // 16777216
#define OFF_STATS   ((size_t)25690112)                 // 1024
#define OFF_CSTATE  ((size_t)25691136)                 // 8192
#define OFF_HX      ((size_t)25699328)                 // 16384 ull = 32768 floats
#define OFF_W2      ((size_t)25732096)                 // 1024
#define OFF_B2      ((size_t)25733120)                 // 16
#define OFF_SAMP    ((size_t)25733136)                 // 32768
#define OFF_HLAST   ((size_t)25765904)                 // 8192 (cross-dispatch handoff)

#define REP16(X) X(0) X(1) X(2) X(3) X(4) X(5) X(6) X(7) X(8) X(9) X(10) X(11) \
  X(12) X(13) X(14) X(15)

// fast transcendentals for the LSTM cell (v_exp_f32 / v_rcp_f32 based; verified r1).
__device__ __forceinline__ float frcp_(float x) { return __builtin_amdgcn_rcpf(x); }
__device__ __forceinline__ float fsig_(float x) { return frcp_(1.f + __expf(-x)); }
__device__ __forceinline__ float ftanh_(float x) {
  float a = fabsf(x);
  float e = __expf(-2.f * a);
  float t = (1.f - e) * frcp_(1.f + e);
  return copysignf(t, x);
}

// ---------------- K0: repack Whh; zero stats + hx tag words ----------------
// wq float4 idx = (dir*4+kq)*16384 + q*1024 + gate*256 + s*32 + jl
__global__ __launch_bounds__(256) void k0_init(
    const float* __restrict__ WhhF, const float* __restrict__ WhhB,
    float4* __restrict__ wq, float* __restrict__ stats, int* __restrict__ hxw) {
  int idx = blockIdx.x * 256 + threadIdx.x;
  if (idx < 131072) {
    int jl = idx & 31, s = (idx >> 5) & 7, gate = (idx >> 8) & 3;
    int q = (idx >> 10) & 15, kq = (idx >> 14) & 3, dir = idx >> 16;
    int row = gate * 256 + s * 32 + jl;
    int col = kq * 64 + q * 4;
    const float* W = (dir ? WhhB : WhhF) + (size_t)row * H + col;
    wq[idx] = make_float4(W[0], W[1], W[2], W[3]);
  }
  if (idx < 1024) stats[idx] = 0.f;
  if (idx < 32768) hxw[idx] = 0;   // tags=0 < any target>=1
}

// ---------------- K12: fused recurrence (blocks < nk2) + next-phase proj GEMM ----
// k2 role: 8 sibling WGs x 512 thr per (dir,b); r1's proven tagged agent-atomic
//   exchange; own slice via LDS; step-0 handoff via plain hlast (stream-ordered).
// k1 role: 64t x 128g tile per block, 512 thr, reg-double-buffered staging; writes
//   proj for phase p1 into the parity buffer k2 is NOT reading this dispatch.
__global__ __launch_bounds__(512, 1) void k12(
    const float4* __restrict__ wq,
    const float* __restrict__ pF2, const float* __restrict__ pB2,   // k2 reads
    float* __restrict__ pF1, float* __restrict__ pB1,               // k1 writes
    const float* __restrict__ x,
    const float* __restrict__ WihF, const float* __restrict__ bihF, const float* __restrict__ bhhF,
    const float* __restrict__ WihB, const float* __restrict__ bihB, const float* __restrict__ bhhB,
    float* __restrict__ hbuf, ull* __restrict__ hx2, float* __restrict__ hlast,
    float* __restrict__ cstate, float* __restrict__ stats,
    int nk2, int t0f2, int t0b2, int first, int ebase, int p1) {
  __shared__ __align__(16) float smem[16 * 68 + 16 * 132];  // 3200 floats, role-overlaid

  if ((int)blockIdx.x < nk2) {
    // ================= k2 role: LSTM recurrence =================
    float* h_lds = smem;          // [256]
    float* pbuf  = smem + 256;    // [512]
    const int tid = threadIdx.x;
    const int l = tid & 63, w = tid >> 6;
    const int jl = tid & 31, gate = (tid >> 5) & 3, kq = tid >> 7;
    const int bx = blockIdx.x;
    const int grp = bx & 31, s = bx >> 5;     // 8 siblings: {g, g+32, ..., g+224}
    const int dir = grp >> 4, b = grp & 15;
    const int row = gate * 256 + s * 32 + jl;

    const float4* wbase = wq + (size_t)(dir * 4 + kq) * 16384 + gate * 256 + s * 32 + jl;
#define WDECL(i) float wx##i, wy##i, wz##i, ww##i; \
    { float4 t_ = wbase[(size_t)(i) * 1024]; \
      wx##i = t_.x; wy##i = t_.y; wz##i = t_.z; ww##i = t_.w; } \
    asm volatile("" : "+v"(wx##i), "+v"(wy##i), "+v"(wz##i), "+v"(ww##i));
    REP16(WDECL)
#undef WDECL

    float c = 0.f, s1 = 0.f, s2 = 0.f;
    if (w == 0 && l < 32 && !first) c = cstate[grp * 256 + s * 32 + l];

    const float* pbase = dir ? pB2 : pF2;
    float pv = 0.f;
    if (kq == 0) {
      int tc0 = dir ? (CHUNK - 1) : 0;
      pv = pbase[((size_t)tc0 * BB + b) * G4H + row];
    }

    for (int step = 0; step < CHUNK; ++step) {
      int abs = ebase + step;

      // acquire h_{abs-1}
      if (tid < 256) {
        if (abs == 0) {
          h_lds[tid] = 0.f;
        } else if (step == 0) {
          h_lds[tid] = hlast[grp * 256 + tid];   // prev dispatch (stream-ordered)
        } else if ((tid >> 5) != s) {            // own slice already in h_lds
          ull* src = hx2 + (size_t)((abs - 1) & 1) * 8192 + grp * 256 + tid;
          ull wd = __hip_atomic_load(src, __ATOMIC_RELAXED, __HIP_MEMORY_SCOPE_AGENT);
          while ((int)(wd >> 32) < abs)
            wd = __hip_atomic_load(src, __ATOMIC_RELAXED, __HIP_MEMORY_SCOPE_AGENT);
          h_lds[tid] = __uint_as_float((unsigned)wd);
        }
      }
      __syncthreads();                          // A: h ready

      float acc = (kq == 0) ? pv : 0.f;
      const float4* h4p = ((const float4*)h_lds) + (kq << 4);
#define WFMA(i) { float4 hv = h4p[i]; \
      acc += wx##i * hv.x + wy##i * hv.y + wz##i * hv.z + ww##i * hv.w; }
      REP16(WFMA)
#undef WFMA
      pbuf[tid] = acc;
      __syncthreads();                          // B: partials ready

      if (w == 0 && l < 32) {
        float gi = pbuf[l]       + pbuf[128 + l] + pbuf[256 + l] + pbuf[384 + l];
        float gf = pbuf[32 + l]  + pbuf[160 + l] + pbuf[288 + l] + pbuf[416 + l];
        float gg = pbuf[64 + l]  + pbuf[192 + l] + pbuf[320 + l] + pbuf[448 + l];
        float go = pbuf[96 + l]  + pbuf[224 + l] + pbuf[352 + l] + pbuf[480 + l];
        float ig = fsig_(gi);
        float fg = fsig_(gf);
        float gz = ftanh_(gg);
        float og = fsig_(go);
        c = fg * c + ig * gz;
        float h = og * ftanh_(c);
        s1 += h; s2 += h * h;
        int j = s * 32 + l;
        h_lds[j] = h;                           // own-slice local publish
        ull wd = ((ull)(unsigned)(abs + 1) << 32) | (ull)__float_as_uint(h);
        __hip_atomic_store(hx2 + (size_t)(abs & 1) * 8192 + grp * 256 + j, wd,
                           __ATOMIC_RELAXED, __HIP_MEMORY_SCOPE_AGENT);
        if (step == CHUNK - 1) hlast[grp * 256 + j] = h;  // next-dispatch handoff
        int tc = dir ? (CHUNK - 1 - step) : step;
        int t = (dir ? t0b2 : t0f2) + tc;
        hbuf[((size_t)t * BB + b) * 512 + dir * 256 + j] = h;
      }
      if (kq == 0 && step + 1 < CHUNK) {        // prefetch next proj
        int tcn = dir ? (CHUNK - 2 - step) : (step + 1);
        pv = pbase[((size_t)tcn * BB + b) * G4H + row];
      }
      // no bottom barrier: next poll + barrier A separates steps
    }

    if (w == 0 && l < 32) {
      cstate[grp * 256 + s * 32 + l] = c;
      atomicAdd(&stats[dir * 256 + s * 32 + l], s1);
      atomicAdd(&stats[512 + dir * 256 + s * 32 + l], s2);
    }
    return;
  }

  // ================= k1 role: proj GEMM for phase p1 =================
  if (p1 < 0) return;
  float* Xs = smem;             // [16][68]
  float* Ws = smem + 16 * 68;   // [16][132]
  int bid = (int)blockIdx.x - nk2;
  int ttile = bid & 1, gtile = (bid >> 1) & 7, zb = bid >> 4;
  int b = zb & 15, dir = zb >> 4;
  const float* Wih = dir ? WihB : WihF;
  const float* bih = dir ? bihB : bihF;
  const float* bhh = dir ? bhhB : bhhF;
  float* proj = dir ? pB1 : pF1;
  int t0 = (dir ? (NPH - 1 - p1) : p1) * CHUNK;
  int tbase = t0 + ttile * 64;
  int gbase = gtile * 128;
  int tid = threadIdx.x;
  int tx = tid & 15, ty = tid >> 4;           // ty 0..31
  float acc[4][4];
#pragma unroll
  for (int i = 0; i < 4; i++)
#pragma unroll
    for (int j = 0; j < 4; j++) acc[i][j] = 0.f;

  int lt = tid & 63, lk = tid >> 6;           // X: 2 rows (lk, lk+8) x 64 t
  int wg = tid >> 2, wc = tid & 3;            // W: 128 g-rows x one float4 of c
  const float* xb = x + (size_t)b * CIN * TT + tbase + lt;
  const float* wp = Wih + (size_t)(gbase + wg) * CIN + 4 * wc;

  float rxa = xb[(size_t)lk * TT];
  float rxb = xb[(size_t)(lk + 8) * TT];
  float4 rw = *(const float4*)wp;

  for (int c0 = 0; c0 < CIN; c0 += 16) {
    __syncthreads();
    Xs[lk * 68 + lt] = rxa;
    Xs[(lk + 8) * 68 + lt] = rxb;
    Ws[(4 * wc + 0) * 132 + wg] = rw.x;
    Ws[(4 * wc + 1) * 132 + wg] = rw.y;
    Ws[(4 * wc + 2) * 132 + wg] = rw.z;
    Ws[(4 * wc + 3) * 132 + wg] = rw.w;
    __syncthreads();
    if (c0 + 16 < CIN) {
      rxa = xb[(size_t)(c0 + 16 + lk) * TT];
      rxb = xb[(size_t)(c0 + 16 + lk + 8) * TT];
      rw  = *(const float4*)(wp + c0 + 16);
    }
#pragma unroll
    for (int kk = 0; kk < 16; kk++) {
      float4 av = *(const float4*)&Xs[kk * 68 + tx * 4];
      float4 bv = *(const float4*)&Ws[kk * 132 + ty * 4];
      acc[0][0] += av.x * bv.x; acc[0][1] += av.x * bv.y; acc[0][2] += av.x * bv.z; acc[0][3] += av.x * bv.w;
      acc[1][0] += av.y * bv.x; acc[1][1] += av.y * bv.y; acc[1][2] += av.y * bv.z; acc[1][3] += av.y * bv.w;
      acc[2][0] += av.z * bv.x; acc[2][1] += av.z * bv.y; acc[2][2] += av.z * bv.z; acc[2][3] += av.z * bv.w;
      acc[3][0] += av.w * bv.x; acc[3][1] += av.w * bv.y; acc[3][2] += av.w * bv.z; acc[3][3] += av.w * bv.w;
    }
  }
  int g0 = gbase + ty * 4;
  float bias0 = bih[g0 + 0] + bhh[g0 + 0];
  float bias1 = bih[g0 + 1] + bhh[g0 + 1];
  float bias2 = bih[g0 + 2] + bhh[g0 + 2];
  float bias3 = bih[g0 + 3] + bhh[g0 + 3];
#pragma unroll
  for (int i = 0; i < 4; i++) {
    int tc = ttile * 64 + tx * 4 + i;
    float4 st = make_float4(acc[i][0] + bias0, acc[i][1] + bias1,
                            acc[i][2] + bias2, acc[i][3] + bias3);
    *(float4*)(proj + ((size_t)tc * BB + b) * G4H + g0) = st;
  }
}

// ---------------- K3: fold BN into linear ----------------
__global__ __launch_bounds__(512) void k3_prep(
    const float* __restrict__ stats, const float* __restrict__ gamma,
    const float* __restrict__ beta, const float* __restrict__ Wlin,
    const float* __restrict__ blin, float* __restrict__ w2, float* __restrict__ b2) {
  __shared__ float r0[512], r1[512];
  int ch = threadIdx.x;
  float mean = stats[ch] * (1.f / 32768.f);
  float var  = stats[512 + ch] * (1.f / 32768.f) - mean * mean;
  float sc = gamma[ch] * rsqrtf(var + 1e-5f);
  float w0 = Wlin[ch], w1 = Wlin[512 + ch];
  w2[ch] = w0 * sc; w2[512 + ch] = w1 * sc;
  float tt = beta[ch] - mean * sc;
  r0[ch] = w0 * tt; r1[ch] = w1 * tt;
  __syncthreads();
  for (int off = 256; off > 0; off >>= 1) {
    if (ch < off) { r0[ch] += r0[ch + off]; r1[ch] += r1[ch + off]; }
    __syncthreads();
  }
  if (ch == 0) { b2[0] = blin[0] + r0[0]; b2[1] = blin[1] + r1[0]; }
}

// ---------------- K4: posterior + gumbel hard sample; one wave per (b,t) ----------------
__global__ __launch_bounds__(256) void k4_post(
    const float* __restrict__ hbuf, const float* __restrict__ w2,
    const float* __restrict__ b2, const float* __restrict__ u,
    const float* __restrict__ e, float* __restrict__ post,
    float* __restrict__ samp) {
  int wid = (blockIdx.x * 256 + threadIdx.x) >> 6;
  int lane = threadIdx.x & 63;
  int b = wid >> 11, t = wid & 2047;
  const float* hr = hbuf + ((size_t)t * BB + b) * 512;
  int c0 = lane * 8;
  float4 h0 = *(const float4*)(hr + c0);
  float4 h1 = *(const float4*)(hr + c0 + 4);
  float4 wa = *(const float4*)(w2 + c0);
  float4 wb = *(const float4*)(w2 + c0 + 4);
  float4 va = *(const float4*)(w2 + 512 + c0);
  float4 vb = *(const float4*)(w2 + 512 + c0 + 4);
  float d0 = h0.x * wa.x + h0.y * wa.y + h0.z * wa.z + h0.w * wa.w
           + h1.x * wb.x + h1.y * wb.y + h1.z * wb.z + h1.w * wb.w;
  float d1 = h0.x * va.x + h0.y * va.y + h0.z * va.z + h0.w * va.w
           + h1.x * vb.x + h1.y * vb.y + h1.z * vb.z + h1.w * vb.w;
#pragma unroll
  for (int off = 32; off > 0; off >>= 1) {
    d0 += __shfl_xor(d0, off, 64);
    d1 += __shfl_xor(d1, off, 64);
  }
  if (lane == 0) {
    float z0 = (d0 + b2[0]) * 0.1f, z1 = (d1 + b2[1]) * 0.1f;
    float m = fmaxf(z0, z1);
    float e0 = expf(z0 - m), e1 = expf(z1 - m);
    float inv = 1.f / (e0 + e1);
    float p0 = e0 * inv, p1 = e1 * inv;
    size_t o = (size_t)b * TT + t;
    post[o * 2] = p0; post[o * 2 + 1] = p1;
    float u0 = u[o * 2], u1 = u[o * 2 + 1];
    float g0 = -logf(-logf(u0 + 1e-20f) + 1e-20f);
    float g1 = -logf(-logf(u1 + 1e-20f) + 1e-20f);
    float a0 = logf(p0) + g0, a1 = logf(p1) + g1;
    samp[o] = (a1 > a0) ? e[o] : 0.f;  // strict >: np.argmax tie -> class 0
  }
}

// ---------------- K5: 3x median-of-5 (reflect pad), one WG per b ----------------
#define MSWAP(a, b) { float lo_ = fminf(a, b); b = fmaxf(a, b); a = lo_; }
__global__ __launch_bounds__(256) void k5_median(
    const float* __restrict__ samp, float* __restrict__ mask) {
  __shared__ float buf[2][TT];
  int b = blockIdx.x, tid = threadIdx.x;
  for (int i = tid; i < TT; i += 256) buf[0][i] = samp[(size_t)b * TT + i];
  __syncthreads();
  int src = 0;
  for (int pass = 0; pass < 3; ++pass) {
    for (int i = tid; i < TT; i += 256) {
      float v0, v1, v2, v3, v4;
      {
        int i0 = i - 2; i0 = i0 < 0 ? -i0 : i0;
        int i1 = i - 1; i1 = i1 < 0 ? -i1 : i1;
        int i3 = i + 1; i3 = i3 > TT - 1 ? 2 * (TT - 1) - i3 : i3;
        int i4 = i + 2; i4 = i4 > TT - 1 ? 2 * (TT - 1) - i4 : i4;
        v0 = buf[src][i0]; v1 = buf[src][i1]; v2 = buf[src][i];
        v3 = buf[src][i3]; v4 = buf[src][i4];
      }
      MSWAP(v0, v1); MSWAP(v3, v4); MSWAP(v2, v4); MSWAP(v2, v3);
      MSWAP(v1, v4); MSWAP(v0, v3); MSWAP(v0, v2); MSWAP(v1, v3);
      MSWAP(v1, v2);
      buf[1 - src][i] = v2;
    }
    __syncthreads();
    src = 1 - src;
  }
  for (int i = tid; i < TT; i += 256) mask[(size_t)b * TT + i] = buf[src][i];
}

extern "C" void kernel_launch(void* const* d_in, const int* in_sizes, int n_in,
                              void* d_out, int out_size, void* d_ws, size_t ws_size,
                              hipStream_t stream) {
  const float* x    = (const float*)d_in[0];
  const float* e    = (const float*)d_in[1];
  const float* u    = (const float*)d_in[2];
  const float* WihF = (const float*)d_in[3];
  const float* WhhF = (const float*)d_in[4];
  const float* bihF = (const float*)d_in[5];
  const float* bhhF = (const float*)d_in[6];
  const float* WihB = (const float*)d_in[7];
  const float* WhhB = (const float*)d_in[8];
  const float* bihB = (const float*)d_in[9];
  const float* bhhB = (const float*)d_in[10];
  const float* gamma= (const float*)d_in[11];
  const float* beta = (const float*)d_in[12];
  const float* Wlin = (const float*)d_in[13];
  const float* blin = (const float*)d_in[14];

  float* ws = (float*)d_ws;
  float4* wq    = (float4*)(ws + OFF_WQ);
  float* pf[2]  = { ws + OFF_PF0, ws + OFF_PF1 };
  float* pb[2]  = { ws + OFF_PB0, ws + OFF_PB1 };
  float* hbuf   = ws + OFF_HBUF;
  float* stats  = ws + OFF_STATS;
  float* cstate = ws + OFF_CSTATE;
  ull*   hx2    = (ull*)(ws + OFF_HX);
  float* w2     = ws + OFF_W2;
  float* b2     = ws + OFF_B2;
  float* samp   = ws + OFF_SAMP;
  float* hlast  = ws + OFF_HLAST;

  float* post = (float*)d_out;
  float* mask = (float*)d_out + (size_t)BB * TT * 2;

  hipLaunchKernelGGL(k0_init, dim3(512), dim3(256), 0, stream,
                     WhhF, WhhB, wq, stats, (int*)hx2);
  // prologue: proj for phase 0 into parity-0 buffers (k1 role only)
  hipLaunchKernelGGL(k12, dim3(512), dim3(512), 0, stream,
                     wq, pf[0], pb[0], pf[0], pb[0], x,
                     WihF, bihF, bhhF, WihB, bihB, bhhB,
                     hbuf, hx2, hlast, cstate, stats,
                     0, 0, 0, 1, 0, 0);
  for (int p = 0; p < NPH; ++p) {
    int q = p & 1;
    int np1 = (p + 1 < NPH) ? (p + 1) : -1;
    int nblk = 256 + ((np1 >= 0) ? 512 : 0);
    hipLaunchKernelGGL(k12, dim3(nblk), dim3(512), 0, stream,
                       wq, pf[q], pb[q], pf[q ^ 1], pb[q ^ 1], x,
                       WihF, bihF, bhhF, WihB, bihB, bhhB,
                       hbuf, hx2, hlast, cstate, stats,
                       256, p * CHUNK, (NPH - 1 - p) * CHUNK,
                       p == 0 ? 1 : 0, p * CHUNK, np1);
  }
  hipLaunchKernelGGL(k3_prep, dim3(1), dim3(512), 0, stream,
                     stats, gamma, beta, Wlin, blin, w2, b2);
  hipLaunchKernelGGL(k4_post, dim3(8192), dim3(256), 0, stream,
                     hbuf, w2, b2, u, e, post, samp);
  hipLaunchKernelGGL(k5_median, dim3(16), dim3(256), 0, stream, samp, mask);
}